// Round 2
// baseline (1053.449 us; speedup 1.0000x reference)
//
#include <hip/hip_runtime.h>

#define N_NODES 100000
#define F_IN    128
#define H_DIM   64
#define C_DIM   16

__device__ __forceinline__ void fma4(float4& acc, float s, const float4& w) {
    acc.x = fmaf(s, w.x, acc.x);
    acc.y = fmaf(s, w.y, acc.y);
    acc.z = fmaf(s, w.z, acc.z);
    acc.w = fmaf(s, w.w, acc.w);
}

// ---------- degree ----------
__global__ void k_init_deg(float* deg) {
    int i = blockIdx.x * blockDim.x + threadIdx.x;
    if (i < N_NODES) deg[i] = 1.0f;   // the "+1.0" self loop
}

__global__ void k_count_deg(const int* __restrict__ edges, float* deg, int E) {
    int stride = gridDim.x * blockDim.x;
    for (int e = blockIdx.x * blockDim.x + threadIdx.x; e < E; e += stride) {
        int dst = edges[2 * e + 1];
        atomicAdd(&deg[dst], 1.0f);   // exact: integer-valued f32 < 2^24
    }
}

__global__ void k_rsqrt(float* deg) {
    int i = blockIdx.x * blockDim.x + threadIdx.x;
    if (i < N_NODES) deg[i] = rsqrtf(deg[i]);
}

// ---------- GEMM1: h1[N,64] = x[N,128] @ W1[128,64] ----------
// block = 256 threads -> 16 rows x 64 cols, each thread 1 row x 4 cols.
__global__ __launch_bounds__(256) void k_gemm1(const float* __restrict__ x,
                                               const float* __restrict__ W1,
                                               float* __restrict__ h1) {
    __shared__ float4 wlds[F_IN * 16];               // 128 k x 16 col-quads = 32 KB
    int tid = threadIdx.x;
    const float4* w4 = (const float4*)W1;
    #pragma unroll
    for (int i = 0; i < 8; ++i) wlds[tid + 256 * i] = w4[tid + 256 * i];
    __syncthreads();

    int row  = blockIdx.x * 16 + (tid >> 4);         // N = 6250*16 exactly
    int colq = tid & 15;
    const float4* x4 = (const float4*)(x + (size_t)row * F_IN);
    float4 acc = {0.f, 0.f, 0.f, 0.f};
    #pragma unroll
    for (int k4 = 0; k4 < F_IN / 4; ++k4) {
        float4 xv = x4[k4];
        fma4(acc, xv.x, wlds[(4 * k4 + 0) * 16 + colq]);
        fma4(acc, xv.y, wlds[(4 * k4 + 1) * 16 + colq]);
        fma4(acc, xv.z, wlds[(4 * k4 + 2) * 16 + colq]);
        fma4(acc, xv.w, wlds[(4 * k4 + 3) * 16 + colq]);
    }
    ((float4*)(h1 + (size_t)row * H_DIM))[colq] = acc;
}

// ---------- self term layer 1: agg1 = h1 * dinv^2 + b1 ----------
__global__ void k_self1(const float* __restrict__ h1, const float* __restrict__ dinv,
                        const float* __restrict__ b1, float* __restrict__ agg1) {
    int idx = blockIdx.x * blockDim.x + threadIdx.x;  // over N*16 float4, exact grid
    int i = idx >> 4, jq = idx & 15;
    float d = dinv[i];
    float dd = d * d;
    float4 hv = ((const float4*)h1)[idx];
    float4 bv = ((const float4*)b1)[jq];
    float4 r  = { fmaf(hv.x, dd, bv.x), fmaf(hv.y, dd, bv.y),
                  fmaf(hv.z, dd, bv.z), fmaf(hv.w, dd, bv.w) };
    ((float4*)agg1)[idx] = r;
}

// ---------- scatter layer 1: one wave per edge, lane = feature ----------
__global__ void k_scatter1(const int* __restrict__ edges,
                           const float* __restrict__ h1,
                           const float* __restrict__ dinv,
                           float* agg1, int E) {
    int gid  = blockIdx.x * blockDim.x + threadIdx.x;
    int wave = gid >> 6;
    int lane = threadIdx.x & 63;
    int nw   = (gridDim.x * blockDim.x) >> 6;
    for (int e = wave; e < E; e += nw) {
        int src = edges[2 * e];
        int dst = edges[2 * e + 1];
        float norm = dinv[src] * dinv[dst];
        atomicAdd(&agg1[(size_t)dst * H_DIM + lane],
                  norm * h1[(size_t)src * H_DIM + lane]);
    }
}

// ---------- GEMM2: h2[N,16] = relu(agg1)[N,64] @ W2[64,16] ----------
// block = 256 -> 64 rows x 16 cols, each thread 1 row x 4 cols. relu fused on load.
__global__ __launch_bounds__(256) void k_gemm2(const float* __restrict__ hpre,
                                               const float* __restrict__ W2,
                                               float* __restrict__ h2) {
    __shared__ float4 wlds[H_DIM * 4];                // 64 k x 4 col-quads = 4 KB
    int tid = threadIdx.x;
    if (tid < H_DIM * 4) wlds[tid] = ((const float4*)W2)[tid];
    __syncthreads();

    int row = blockIdx.x * 64 + (tid >> 2);
    if (row >= N_NODES) return;
    int colq = tid & 3;
    const float4* h4 = (const float4*)(hpre + (size_t)row * H_DIM);
    float4 acc = {0.f, 0.f, 0.f, 0.f};
    #pragma unroll
    for (int k4 = 0; k4 < H_DIM / 4; ++k4) {
        float4 hv = h4[k4];
        hv.x = fmaxf(hv.x, 0.f); hv.y = fmaxf(hv.y, 0.f);
        hv.z = fmaxf(hv.z, 0.f); hv.w = fmaxf(hv.w, 0.f);
        fma4(acc, hv.x, wlds[(4 * k4 + 0) * 4 + colq]);
        fma4(acc, hv.y, wlds[(4 * k4 + 1) * 4 + colq]);
        fma4(acc, hv.z, wlds[(4 * k4 + 2) * 4 + colq]);
        fma4(acc, hv.w, wlds[(4 * k4 + 3) * 4 + colq]);
    }
    ((float4*)(h2 + (size_t)row * C_DIM))[colq] = acc;
}

// ---------- self term layer 2 (writes d_out): out = h2 * dinv^2 + b2 ----------
__global__ void k_self2(const float* __restrict__ h2, const float* __restrict__ dinv,
                        const float* __restrict__ b2, float* __restrict__ out) {
    int idx = blockIdx.x * blockDim.x + threadIdx.x;  // over N*4 float4
    if (idx >= N_NODES * 4) return;
    int i = idx >> 2, jq = idx & 3;
    float d = dinv[i];
    float dd = d * d;
    float4 hv = ((const float4*)h2)[idx];
    float4 bv = ((const float4*)b2)[jq];
    float4 r  = { fmaf(hv.x, dd, bv.x), fmaf(hv.y, dd, bv.y),
                  fmaf(hv.z, dd, bv.z), fmaf(hv.w, dd, bv.w) };
    ((float4*)out)[idx] = r;
}

// ---------- scatter layer 2: 16 lanes per edge ----------
__global__ void k_scatter2(const int* __restrict__ edges,
                           const float* __restrict__ h2,
                           const float* __restrict__ dinv,
                           float* out, int E) {
    int gid  = blockIdx.x * blockDim.x + threadIdx.x;
    int grp  = gid >> 4;
    int lane = gid & 15;
    int ng   = (gridDim.x * blockDim.x) >> 4;
    for (int e = grp; e < E; e += ng) {
        int src = edges[2 * e];
        int dst = edges[2 * e + 1];
        float norm = dinv[src] * dinv[dst];
        atomicAdd(&out[(size_t)dst * C_DIM + lane],
                  norm * h2[(size_t)src * C_DIM + lane]);
    }
}

extern "C" void kernel_launch(void* const* d_in, const int* in_sizes, int n_in,
                              void* d_out, int out_size, void* d_ws, size_t ws_size,
                              hipStream_t stream) {
    const float* x     = (const float*)d_in[0];
    const int*   edges = (const int*)d_in[1];              // int32 (harness converts)
    const float* W1    = (const float*)d_in[2];
    const float* b1    = (const float*)d_in[3];
    const float* W2    = (const float*)d_in[4];
    const float* b2    = (const float*)d_in[5];
    float*       out   = (float*)d_out;

    const int E = in_sizes[1] / 2;                         // 3,200,000

    // workspace layout (f32): h1 (aliased by h2) | agg1 | deg   (~52 MB)
    float* h1   = (float*)d_ws;
    float* agg1 = h1   + (size_t)N_NODES * H_DIM;
    float* deg  = agg1 + (size_t)N_NODES * H_DIM;
    float* h2   = h1;   // h1 dead after k_scatter1; k_gemm2 reads only agg1

    // degree -> dinv
    k_init_deg <<<(N_NODES + 255) / 256, 256, 0, stream>>>(deg);
    k_count_deg<<<2048, 256, 0, stream>>>(edges, deg, E);
    k_rsqrt    <<<(N_NODES + 255) / 256, 256, 0, stream>>>(deg);

    // layer 1
    k_gemm1    <<<N_NODES / 16, 256, 0, stream>>>(x, W1, h1);
    k_self1    <<<(N_NODES * 16) / 256, 256, 0, stream>>>(h1, deg, b1, agg1);
    k_scatter1 <<<4096, 256, 0, stream>>>(edges, h1, deg, agg1, E);

    // layer 2 (relu fused into gemm2 load)
    k_gemm2    <<<(N_NODES + 63) / 64, 256, 0, stream>>>(agg1, W2, h2);
    k_self2    <<<(N_NODES * 4 + 255) / 256, 256, 0, stream>>>(h2, deg, b2, out);
    k_scatter2 <<<4096, 256, 0, stream>>>(edges, h2, deg, out, E);
}

// Round 3
// 629.452 us; speedup vs baseline: 1.6736x; 1.6736x over previous
//
#include <hip/hip_runtime.h>

#define N_NODES 100000
#define F_IN    128
#define H_DIM   64
#define C_DIM   16

__device__ __forceinline__ void fma4(float4& acc, float s, const float4& w) {
    acc.x = fmaf(s, w.x, acc.x);
    acc.y = fmaf(s, w.y, acc.y);
    acc.z = fmaf(s, w.z, acc.z);
    acc.w = fmaf(s, w.w, acc.w);
}

// ---------- CSR build ----------
__global__ void k_zero(int* __restrict__ cnt, int* __restrict__ counter) {
    int i = blockIdx.x * blockDim.x + threadIdx.x;
    if (i < N_NODES) cnt[i] = 0;
    if (i == 0) *counter = 0;
}

__global__ void k_hist(const int* __restrict__ edges, int* __restrict__ cnt, int E) {
    int stride = gridDim.x * blockDim.x;
    for (int e = blockIdx.x * blockDim.x + threadIdx.x; e < E; e += stride) {
        atomicAdd(&cnt[edges[2 * e + 1]], 1);
    }
}

// per-block inclusive scan of cnt + one atomic per block => base offsets.
// Segment order across nodes is arbitrary (block completion order) — valid CSR,
// only changes FP summation order (already nondeterministic with atomics).
__global__ __launch_bounds__(256) void k_alloc(const int* __restrict__ cnt,
                                               int* __restrict__ base,
                                               int* __restrict__ row_cur,
                                               float* __restrict__ dinv,
                                               int* counter) {
    __shared__ int s[256];
    __shared__ int blockBase;
    int tid = threadIdx.x;
    int gi  = blockIdx.x * 256 + tid;
    int c   = (gi < N_NODES) ? cnt[gi] : 0;
    s[tid] = c;
    __syncthreads();
    #pragma unroll
    for (int off = 1; off < 256; off <<= 1) {
        int v = (tid >= off) ? s[tid - off] : 0;
        __syncthreads();
        s[tid] += v;
        __syncthreads();
    }
    if (tid == 255) blockBase = atomicAdd(counter, s[255]);
    __syncthreads();
    if (gi < N_NODES) {
        int b = blockBase + s[tid] - c;
        base[gi]    = b;
        row_cur[gi] = b;
        dinv[gi]    = rsqrtf((float)(c + 1));   // deg = cnt + 1 (self loop)
    }
}

__global__ void k_fill(const int* __restrict__ edges, int* __restrict__ row_cur,
                       int* __restrict__ csr_src, int E) {
    int stride = gridDim.x * blockDim.x;
    for (int e = blockIdx.x * blockDim.x + threadIdx.x; e < E; e += stride) {
        int2 ed = ((const int2*)edges)[e];              // (src, dst)
        int pos = atomicAdd(&row_cur[ed.y], 1);
        csr_src[pos] = ed.x;
    }
}

// ---------- GEMM1: h1[N,64] = x[N,128] @ W1[128,64] ----------
__global__ __launch_bounds__(256) void k_gemm1(const float* __restrict__ x,
                                               const float* __restrict__ W1,
                                               float* __restrict__ h1) {
    __shared__ float4 wlds[F_IN * 16];               // 32 KB
    int tid = threadIdx.x;
    const float4* w4 = (const float4*)W1;
    #pragma unroll
    for (int i = 0; i < 8; ++i) wlds[tid + 256 * i] = w4[tid + 256 * i];
    __syncthreads();

    int row  = blockIdx.x * 16 + (tid >> 4);         // N = 6250*16 exactly
    int colq = tid & 15;
    const float4* x4 = (const float4*)(x + (size_t)row * F_IN);
    float4 acc = {0.f, 0.f, 0.f, 0.f};
    #pragma unroll
    for (int k4 = 0; k4 < F_IN / 4; ++k4) {
        float4 xv = x4[k4];
        fma4(acc, xv.x, wlds[(4 * k4 + 0) * 16 + colq]);
        fma4(acc, xv.y, wlds[(4 * k4 + 1) * 16 + colq]);
        fma4(acc, xv.z, wlds[(4 * k4 + 2) * 16 + colq]);
        fma4(acc, xv.w, wlds[(4 * k4 + 3) * 16 + colq]);
    }
    ((float4*)(h1 + (size_t)row * H_DIM))[colq] = acc;
}

// ---------- gather layer 1: one wave per node, lane = feature ----------
// agg1[i] = b1 + dinv[i] * ( dinv[i]*h1[i] + sum_{src in N(i)} dinv[src]*h1[src] )
__global__ __launch_bounds__(256) void k_gather1(const int* __restrict__ csr_src,
                                                 const int* __restrict__ base,
                                                 const int* __restrict__ cnt,
                                                 const float* __restrict__ dinv,
                                                 const float* __restrict__ h1,
                                                 const float* __restrict__ b1,
                                                 float* __restrict__ agg1) {
    int wid  = (blockIdx.x * blockDim.x + threadIdx.x) >> 6;   // node id
    int lane = threadIdx.x & 63;
    if (wid >= N_NODES) return;
    int   b  = base[wid];
    int   c  = cnt[wid];
    float di = dinv[wid];
    float acc = di * h1[(size_t)wid * H_DIM + lane];
    #pragma unroll 4
    for (int k = 0; k < c; ++k) {
        int s = csr_src[b + k];
        acc = fmaf(dinv[s], h1[(size_t)s * H_DIM + lane], acc);
    }
    agg1[(size_t)wid * H_DIM + lane] = fmaf(di, acc, b1[lane]);
}

// ---------- GEMM2: h2[N,16] = relu(agg1)[N,64] @ W2[64,16] ----------
__global__ __launch_bounds__(256) void k_gemm2(const float* __restrict__ hpre,
                                               const float* __restrict__ W2,
                                               float* __restrict__ h2) {
    __shared__ float4 wlds[H_DIM * 4];                // 4 KB
    int tid = threadIdx.x;
    if (tid < H_DIM * 4) wlds[tid] = ((const float4*)W2)[tid];
    __syncthreads();

    int row = blockIdx.x * 64 + (tid >> 2);
    if (row >= N_NODES) return;
    int colq = tid & 3;
    const float4* h4 = (const float4*)(hpre + (size_t)row * H_DIM);
    float4 acc = {0.f, 0.f, 0.f, 0.f};
    #pragma unroll
    for (int k4 = 0; k4 < H_DIM / 4; ++k4) {
        float4 hv = h4[k4];
        hv.x = fmaxf(hv.x, 0.f); hv.y = fmaxf(hv.y, 0.f);
        hv.z = fmaxf(hv.z, 0.f); hv.w = fmaxf(hv.w, 0.f);
        fma4(acc, hv.x, wlds[(4 * k4 + 0) * 4 + colq]);
        fma4(acc, hv.y, wlds[(4 * k4 + 1) * 4 + colq]);
        fma4(acc, hv.z, wlds[(4 * k4 + 2) * 4 + colq]);
        fma4(acc, hv.w, wlds[(4 * k4 + 3) * 4 + colq]);
    }
    ((float4*)(h2 + (size_t)row * C_DIM))[colq] = acc;
}

// ---------- gather layer 2: 16 lanes per node ----------
__global__ __launch_bounds__(256) void k_gather2(const int* __restrict__ csr_src,
                                                 const int* __restrict__ base,
                                                 const int* __restrict__ cnt,
                                                 const float* __restrict__ dinv,
                                                 const float* __restrict__ h2,
                                                 const float* __restrict__ b2,
                                                 float* __restrict__ out) {
    int node = (blockIdx.x * blockDim.x + threadIdx.x) >> 4;
    int lane = threadIdx.x & 15;
    if (node >= N_NODES) return;
    int   b  = base[node];
    int   c  = cnt[node];
    float di = dinv[node];
    float acc = di * h2[(size_t)node * C_DIM + lane];
    #pragma unroll 4
    for (int k = 0; k < c; ++k) {
        int s = csr_src[b + k];
        acc = fmaf(dinv[s], h2[(size_t)s * C_DIM + lane], acc);
    }
    out[(size_t)node * C_DIM + lane] = fmaf(di, acc, b2[lane]);
}

extern "C" void kernel_launch(void* const* d_in, const int* in_sizes, int n_in,
                              void* d_out, int out_size, void* d_ws, size_t ws_size,
                              hipStream_t stream) {
    const float* x     = (const float*)d_in[0];
    const int*   edges = (const int*)d_in[1];              // int32 (harness converts)
    const float* W1    = (const float*)d_in[2];
    const float* b1    = (const float*)d_in[3];
    const float* W2    = (const float*)d_in[4];
    const float* b2    = (const float*)d_in[5];
    float*       out   = (float*)d_out;

    const int E = in_sizes[1] / 2;                         // 3,200,000

    // workspace layout (~65.6 MB)
    float* h1      = (float*)d_ws;                         // N*64
    float* agg1    = h1 + (size_t)N_NODES * H_DIM;         // N*64
    float* dinv    = agg1 + (size_t)N_NODES * H_DIM;       // N
    int*   cnt     = (int*)(dinv + N_NODES);               // N
    int*   base    = cnt + N_NODES;                        // N
    int*   row_cur = base + N_NODES;                       // N
    int*   csr_src = row_cur + N_NODES;                    // E
    int*   counter = csr_src + E;                          // 1
    float* h2      = h1;   // h1 dead after k_gather1; k_gemm2 reads only agg1

    const int nblk = (N_NODES + 255) / 256;

    // CSR build
    k_zero  <<<nblk, 256, 0, stream>>>(cnt, counter);
    k_hist  <<<2048, 256, 0, stream>>>(edges, cnt, E);
    k_alloc <<<nblk, 256, 0, stream>>>(cnt, base, row_cur, dinv, counter);
    k_fill  <<<2048, 256, 0, stream>>>(edges, row_cur, csr_src, E);

    // layer 1
    k_gemm1   <<<N_NODES / 16, 256, 0, stream>>>(x, W1, h1);
    k_gather1 <<<(N_NODES * 64 + 255) / 256, 256, 0, stream>>>(csr_src, base, cnt,
                                                               dinv, h1, b1, agg1);

    // layer 2 (relu fused into gemm2 load)
    k_gemm2   <<<(N_NODES + 63) / 64, 256, 0, stream>>>(agg1, W2, h2);
    k_gather2 <<<(N_NODES * 16 + 255) / 256, 256, 0, stream>>>(csr_src, base, cnt,
                                                               dinv, h2, b2, out);
}

// Round 4
// 331.496 us; speedup vs baseline: 3.1779x; 1.8988x over previous
//
#include <hip/hip_runtime.h>

#define N_NODES 100000
#define F_IN    128
#define H_DIM   64
#define C_DIM   16
#define NBKT    391            // ceil(100000 / 256) buckets of 256 nodes (dst>>8)
#define BKT_PAD 16             // one bucket counter per 64B line (atomic line-serialization)
#define CHUNK   4096           // edges per block in bucket phases

__device__ __forceinline__ void fma4(float4& acc, float s, const float4& w) {
    acc.x = fmaf(s, w.x, acc.x);
    acc.y = fmaf(s, w.y, acc.y);
    acc.z = fmaf(s, w.z, acc.z);
    acc.w = fmaf(s, w.w, acc.w);
}

// ---------- CSR build: two-level bucketed counting sort ----------
__global__ void k_zero_b(int* __restrict__ b) {
    int i = blockIdx.x * blockDim.x + threadIdx.x;
    if (i < NBKT * BKT_PAD) b[i] = 0;
}

__global__ __launch_bounds__(256) void k_bhist(const int2* __restrict__ edges,
                                               int* __restrict__ bkt_tot, int E) {
    __shared__ int cnt[NBKT];
    for (int t = threadIdx.x; t < NBKT; t += 256) cnt[t] = 0;
    __syncthreads();
    int base = blockIdx.x * CHUNK;
    #pragma unroll
    for (int i = 0; i < CHUNK / 256; ++i) {
        int e = base + i * 256 + threadIdx.x;
        if (e < E) atomicAdd(&cnt[edges[e].y >> 8], 1);
    }
    __syncthreads();
    for (int t = threadIdx.x; t < NBKT; t += 256)
        if (cnt[t]) atomicAdd(&bkt_tot[t * BKT_PAD], cnt[t]);
}

__global__ __launch_bounds__(512) void k_bscan(const int* __restrict__ bkt_tot,
                                               int* __restrict__ bkt_base,
                                               int* __restrict__ bkt_tail) {
    __shared__ int s[512];
    int t = threadIdx.x;
    int v = (t < NBKT) ? bkt_tot[t * BKT_PAD] : 0;
    s[t] = v;
    __syncthreads();
    #pragma unroll
    for (int off = 1; off < 512; off <<= 1) {
        int u = (t >= off) ? s[t - off] : 0;
        __syncthreads();
        s[t] += u;
        __syncthreads();
    }
    if (t < NBKT) {
        int b = s[t] - v;                   // exclusive scan
        bkt_base[t] = b;
        bkt_tail[t * BKT_PAD] = b;
    }
}

__global__ __launch_bounds__(256) void k_bfill(const int2* __restrict__ edges,
                                               int* __restrict__ bkt_tail,
                                               int2* __restrict__ pairs, int E) {
    __shared__ int cnt[NBKT];
    __shared__ int row[NBKT];
    for (int t = threadIdx.x; t < NBKT; t += 256) cnt[t] = 0;
    __syncthreads();
    int base = blockIdx.x * CHUNK;
    int2 ed[CHUNK / 256];                   // 16 int2 in registers (static idx via unroll)
    #pragma unroll
    for (int i = 0; i < CHUNK / 256; ++i) {
        int e = base + i * 256 + threadIdx.x;
        if (e < E) { ed[i] = edges[e]; atomicAdd(&cnt[ed[i].y >> 8], 1); }
    }
    __syncthreads();
    for (int t = threadIdx.x; t < NBKT; t += 256)
        row[t] = cnt[t] ? atomicAdd(&bkt_tail[t * BKT_PAD], cnt[t]) : 0;
    __syncthreads();
    #pragma unroll
    for (int i = 0; i < CHUNK / 256; ++i) {
        int e = base + i * 256 + threadIdx.x;
        if (e < E) {
            int r = atomicAdd(&row[ed[i].y >> 8], 1);   // LDS atomic
            pairs[r] = ed[i];
        }
    }
}

// one block per bucket: node-ordered base/cnt/dinv + dense CSR scatter (L2-hot region)
__global__ __launch_bounds__(256) void k_bnode(const int2* __restrict__ pairs,
                                               const int* __restrict__ bkt_base,
                                               int* __restrict__ csr_src,
                                               int* __restrict__ node_base,
                                               int* __restrict__ node_cnt,
                                               float* __restrict__ dinv, int E) {
    __shared__ int cnt[256];
    __shared__ int s[256];
    __shared__ int row[256];
    int b = blockIdx.x;
    int t = threadIdx.x;
    cnt[t] = 0;
    __syncthreads();
    int start = bkt_base[b];
    int end   = (b + 1 < NBKT) ? bkt_base[b + 1] : E;
    for (int e = start + t; e < end; e += 256)
        atomicAdd(&cnt[pairs[e].y & 255], 1);
    __syncthreads();
    int c = cnt[t];
    s[t] = c;
    __syncthreads();
    #pragma unroll
    for (int off = 1; off < 256; off <<= 1) {
        int u = (t >= off) ? s[t - off] : 0;
        __syncthreads();
        s[t] += u;
        __syncthreads();
    }
    int gbase = start + s[t] - c;
    row[t] = gbase;
    int node = b * 256 + t;
    if (node < N_NODES) {
        node_base[node] = gbase;
        node_cnt[node]  = c;
        dinv[node]      = rsqrtf((float)(c + 1));   // deg = cnt + 1 (self loop)
    }
    __syncthreads();
    for (int e = start + t; e < end; e += 256) {
        int2 p = pairs[e];
        int pos = atomicAdd(&row[p.y & 255], 1);    // LDS atomic
        csr_src[pos] = p.x;
    }
}

// ---------- GEMM1: h1[N,64] = x[N,128] @ W1[128,64] ----------
__global__ __launch_bounds__(256) void k_gemm1(const float* __restrict__ x,
                                               const float* __restrict__ W1,
                                               float* __restrict__ h1) {
    __shared__ float4 wlds[F_IN * 16];               // 32 KB
    int tid = threadIdx.x;
    const float4* w4 = (const float4*)W1;
    #pragma unroll
    for (int i = 0; i < 8; ++i) wlds[tid + 256 * i] = w4[tid + 256 * i];
    __syncthreads();

    int row  = blockIdx.x * 16 + (tid >> 4);         // N = 6250*16 exactly
    int colq = tid & 15;
    const float4* x4 = (const float4*)(x + (size_t)row * F_IN);
    float4 acc = {0.f, 0.f, 0.f, 0.f};
    #pragma unroll
    for (int k4 = 0; k4 < F_IN / 4; ++k4) {
        float4 xv = x4[k4];
        fma4(acc, xv.x, wlds[(4 * k4 + 0) * 16 + colq]);
        fma4(acc, xv.y, wlds[(4 * k4 + 1) * 16 + colq]);
        fma4(acc, xv.z, wlds[(4 * k4 + 2) * 16 + colq]);
        fma4(acc, xv.w, wlds[(4 * k4 + 3) * 16 + colq]);
    }
    ((float4*)(h1 + (size_t)row * H_DIM))[colq] = acc;
}

// ---------- gather layer 1: one wave per node, lane = feature ----------
__global__ __launch_bounds__(256) void k_gather1(const int* __restrict__ csr_src,
                                                 const int* __restrict__ base,
                                                 const int* __restrict__ cnt,
                                                 const float* __restrict__ dinv,
                                                 const float* __restrict__ h1,
                                                 const float* __restrict__ b1,
                                                 float* __restrict__ agg1) {
    int wid  = (blockIdx.x * blockDim.x + threadIdx.x) >> 6;   // node id
    int lane = threadIdx.x & 63;
    if (wid >= N_NODES) return;
    int   b  = base[wid];
    int   c  = cnt[wid];
    float di = dinv[wid];
    float acc = di * h1[(size_t)wid * H_DIM + lane];
    #pragma unroll 4
    for (int k = 0; k < c; ++k) {
        int s = csr_src[b + k];
        acc = fmaf(dinv[s], h1[(size_t)s * H_DIM + lane], acc);
    }
    agg1[(size_t)wid * H_DIM + lane] = fmaf(di, acc, b1[lane]);
}

// ---------- GEMM2: h2[N,16] = relu(agg1)[N,64] @ W2[64,16] ----------
__global__ __launch_bounds__(256) void k_gemm2(const float* __restrict__ hpre,
                                               const float* __restrict__ W2,
                                               float* __restrict__ h2) {
    __shared__ float4 wlds[H_DIM * 4];                // 4 KB
    int tid = threadIdx.x;
    if (tid < H_DIM * 4) wlds[tid] = ((const float4*)W2)[tid];
    __syncthreads();

    int row = blockIdx.x * 64 + (tid >> 2);
    if (row >= N_NODES) return;
    int colq = tid & 3;
    const float4* h4 = (const float4*)(hpre + (size_t)row * H_DIM);
    float4 acc = {0.f, 0.f, 0.f, 0.f};
    #pragma unroll
    for (int k4 = 0; k4 < H_DIM / 4; ++k4) {
        float4 hv = h4[k4];
        hv.x = fmaxf(hv.x, 0.f); hv.y = fmaxf(hv.y, 0.f);
        hv.z = fmaxf(hv.z, 0.f); hv.w = fmaxf(hv.w, 0.f);
        fma4(acc, hv.x, wlds[(4 * k4 + 0) * 4 + colq]);
        fma4(acc, hv.y, wlds[(4 * k4 + 1) * 4 + colq]);
        fma4(acc, hv.z, wlds[(4 * k4 + 2) * 4 + colq]);
        fma4(acc, hv.w, wlds[(4 * k4 + 3) * 4 + colq]);
    }
    ((float4*)(h2 + (size_t)row * C_DIM))[colq] = acc;
}

// ---------- gather layer 2: 16 lanes per node ----------
__global__ __launch_bounds__(256) void k_gather2(const int* __restrict__ csr_src,
                                                 const int* __restrict__ base,
                                                 const int* __restrict__ cnt,
                                                 const float* __restrict__ dinv,
                                                 const float* __restrict__ h2,
                                                 const float* __restrict__ b2,
                                                 float* __restrict__ out) {
    int node = (blockIdx.x * blockDim.x + threadIdx.x) >> 4;
    int lane = threadIdx.x & 15;
    if (node >= N_NODES) return;
    int   b  = base[node];
    int   c  = cnt[node];
    float di = dinv[node];
    float acc = di * h2[(size_t)node * C_DIM + lane];
    #pragma unroll 4
    for (int k = 0; k < c; ++k) {
        int s = csr_src[b + k];
        acc = fmaf(dinv[s], h2[(size_t)s * C_DIM + lane], acc);
    }
    out[(size_t)node * C_DIM + lane] = fmaf(di, acc, b2[lane]);
}

extern "C" void kernel_launch(void* const* d_in, const int* in_sizes, int n_in,
                              void* d_out, int out_size, void* d_ws, size_t ws_size,
                              hipStream_t stream) {
    const float* x     = (const float*)d_in[0];
    const int*   edges = (const int*)d_in[1];              // int32 (harness converts)
    const float* W1    = (const float*)d_in[2];
    const float* b1    = (const float*)d_in[3];
    const float* W2    = (const float*)d_in[4];
    const float* b2    = (const float*)d_in[5];
    float*       out   = (float*)d_out;

    const int E = in_sizes[1] / 2;                         // 3,200,000

    // workspace (~65.4 MB):
    // region A (25.6 MB): pairs (CSR build), then h1/h2 (pairs dead after k_bnode)
    float* h1      = (float*)d_ws;                         // N*64 f32
    int2*  pairs   = (int2*)d_ws;                          // E int2 (same bytes)
    float* agg1    = h1 + (size_t)N_NODES * H_DIM;         // N*64 f32
    int*   csr_src = (int*)(agg1 + (size_t)N_NODES * H_DIM); // E
    int*   nbase   = csr_src + E;                          // N
    int*   ncnt    = nbase + N_NODES;                      // N
    float* dinv    = (float*)(ncnt + N_NODES);             // N
    int*   bkt_tot = (int*)(dinv + N_NODES);               // NBKT*16
    int*   bkt_base= bkt_tot + NBKT * BKT_PAD;             // NBKT
    int*   bkt_tail= bkt_base + NBKT;                      // NBKT*16
    float* h2      = h1;

    const int nchunk = (E + CHUNK - 1) / CHUNK;            // 782

    // CSR build (bucketed counting sort by dst)
    k_zero_b <<<(NBKT * BKT_PAD + 255) / 256, 256, 0, stream>>>(bkt_tot);
    k_bhist  <<<nchunk, 256, 0, stream>>>((const int2*)edges, bkt_tot, E);
    k_bscan  <<<1, 512, 0, stream>>>(bkt_tot, bkt_base, bkt_tail);
    k_bfill  <<<nchunk, 256, 0, stream>>>((const int2*)edges, bkt_tail, pairs, E);
    k_bnode  <<<NBKT, 256, 0, stream>>>(pairs, bkt_base, csr_src, nbase, ncnt, dinv, E);

    // layer 1
    k_gemm1   <<<N_NODES / 16, 256, 0, stream>>>(x, W1, h1);
    k_gather1 <<<(N_NODES * 64 + 255) / 256, 256, 0, stream>>>(csr_src, nbase, ncnt,
                                                               dinv, h1, b1, agg1);

    // layer 2 (relu fused into gemm2 load)
    k_gemm2   <<<(N_NODES + 63) / 64, 256, 0, stream>>>(agg1, W2, h2);
    k_gather2 <<<(N_NODES * 16 + 255) / 256, 256, 0, stream>>>(csr_src, nbase, ncnt,
                                                               dinv, h2, b2, out);
}

// Round 5
// 314.604 us; speedup vs baseline: 3.3485x; 1.0537x over previous
//
#include <hip/hip_runtime.h>

#define N_NODES 100000
#define F_IN    128
#define H_DIM   64
#define C_DIM   16
#define NBKT    391            // ceil(100000 / 256) buckets of 256 nodes (dst>>8)
#define BKT_PAD 16             // one bucket counter per 64B line (atomic line-serialization)
#define CHUNK   4096           // edges per block in bucket phases

__device__ __forceinline__ void fma4(float4& acc, float s, const float4& w) {
    acc.x = fmaf(s, w.x, acc.x);
    acc.y = fmaf(s, w.y, acc.y);
    acc.z = fmaf(s, w.z, acc.z);
    acc.w = fmaf(s, w.w, acc.w);
}

// ---------- CSR build: two-level bucketed counting sort ----------
__global__ void k_zero_b(int* __restrict__ b) {
    int i = blockIdx.x * blockDim.x + threadIdx.x;
    if (i < NBKT * BKT_PAD) b[i] = 0;
}

__global__ __launch_bounds__(256) void k_bhist(const int2* __restrict__ edges,
                                               int* __restrict__ bkt_tot, int E) {
    __shared__ int cnt[NBKT];
    for (int t = threadIdx.x; t < NBKT; t += 256) cnt[t] = 0;
    __syncthreads();
    int base = blockIdx.x * CHUNK;
    #pragma unroll
    for (int i = 0; i < CHUNK / 256; ++i) {
        int e = base + i * 256 + threadIdx.x;
        if (e < E) atomicAdd(&cnt[edges[e].y >> 8], 1);
    }
    __syncthreads();
    for (int t = threadIdx.x; t < NBKT; t += 256)
        if (cnt[t]) atomicAdd(&bkt_tot[t * BKT_PAD], cnt[t]);
}

__global__ __launch_bounds__(512) void k_bscan(const int* __restrict__ bkt_tot,
                                               int* __restrict__ bkt_base,
                                               int* __restrict__ bkt_tail) {
    __shared__ int s[512];
    int t = threadIdx.x;
    int v = (t < NBKT) ? bkt_tot[t * BKT_PAD] : 0;
    s[t] = v;
    __syncthreads();
    #pragma unroll
    for (int off = 1; off < 512; off <<= 1) {
        int u = (t >= off) ? s[t - off] : 0;
        __syncthreads();
        s[t] += u;
        __syncthreads();
    }
    if (t < NBKT) {
        int b = s[t] - v;                   // exclusive scan
        bkt_base[t] = b;
        bkt_tail[t * BKT_PAD] = b;
    }
}

__global__ __launch_bounds__(256) void k_bfill(const int2* __restrict__ edges,
                                               int* __restrict__ bkt_tail,
                                               int2* __restrict__ pairs, int E) {
    __shared__ int cnt[NBKT];
    __shared__ int row[NBKT];
    for (int t = threadIdx.x; t < NBKT; t += 256) cnt[t] = 0;
    __syncthreads();
    int base = blockIdx.x * CHUNK;
    int2 ed[CHUNK / 256];                   // 16 int2 in registers (static idx via unroll)
    #pragma unroll
    for (int i = 0; i < CHUNK / 256; ++i) {
        int e = base + i * 256 + threadIdx.x;
        if (e < E) { ed[i] = edges[e]; atomicAdd(&cnt[ed[i].y >> 8], 1); }
    }
    __syncthreads();
    for (int t = threadIdx.x; t < NBKT; t += 256)
        row[t] = cnt[t] ? atomicAdd(&bkt_tail[t * BKT_PAD], cnt[t]) : 0;
    __syncthreads();
    #pragma unroll
    for (int i = 0; i < CHUNK / 256; ++i) {
        int e = base + i * 256 + threadIdx.x;
        if (e < E) {
            int r = atomicAdd(&row[ed[i].y >> 8], 1);   // LDS atomic
            pairs[r] = ed[i];
        }
    }
}

// one block per bucket: node-ordered base/cnt/dinv + dense CSR scatter (L2-hot region)
__global__ __launch_bounds__(256) void k_bnode(const int2* __restrict__ pairs,
                                               const int* __restrict__ bkt_base,
                                               int* __restrict__ csr_src,
                                               int* __restrict__ node_base,
                                               int* __restrict__ node_cnt,
                                               float* __restrict__ dinv, int E) {
    __shared__ int cnt[256];
    __shared__ int s[256];
    __shared__ int row[256];
    int b = blockIdx.x;
    int t = threadIdx.x;
    cnt[t] = 0;
    __syncthreads();
    int start = bkt_base[b];
    int end   = (b + 1 < NBKT) ? bkt_base[b + 1] : E;
    for (int e = start + t; e < end; e += 256)
        atomicAdd(&cnt[pairs[e].y & 255], 1);
    __syncthreads();
    int c = cnt[t];
    s[t] = c;
    __syncthreads();
    #pragma unroll
    for (int off = 1; off < 256; off <<= 1) {
        int u = (t >= off) ? s[t - off] : 0;
        __syncthreads();
        s[t] += u;
        __syncthreads();
    }
    int gbase = start + s[t] - c;
    row[t] = gbase;
    int node = b * 256 + t;
    if (node < N_NODES) {
        node_base[node] = gbase;
        node_cnt[node]  = c;
        dinv[node]      = rsqrtf((float)(c + 1));   // deg = cnt + 1 (self loop)
    }
    __syncthreads();
    for (int e = start + t; e < end; e += 256) {
        int2 p = pairs[e];
        int pos = atomicAdd(&row[p.y & 255], 1);    // LDS atomic
        csr_src[pos] = p.x;
    }
}

// ---------- GEMM1: h1[N,64] = x[N,128] @ W1[128,64] ----------
__global__ __launch_bounds__(256) void k_gemm1(const float* __restrict__ x,
                                               const float* __restrict__ W1,
                                               float* __restrict__ h1) {
    __shared__ float4 wlds[F_IN * 16];               // 32 KB
    int tid = threadIdx.x;
    const float4* w4 = (const float4*)W1;
    #pragma unroll
    for (int i = 0; i < 8; ++i) wlds[tid + 256 * i] = w4[tid + 256 * i];
    __syncthreads();

    int row  = blockIdx.x * 16 + (tid >> 4);         // N = 6250*16 exactly
    int colq = tid & 15;
    const float4* x4 = (const float4*)(x + (size_t)row * F_IN);
    float4 acc = {0.f, 0.f, 0.f, 0.f};
    #pragma unroll
    for (int k4 = 0; k4 < F_IN / 4; ++k4) {
        float4 xv = x4[k4];
        fma4(acc, xv.x, wlds[(4 * k4 + 0) * 16 + colq]);
        fma4(acc, xv.y, wlds[(4 * k4 + 1) * 16 + colq]);
        fma4(acc, xv.z, wlds[(4 * k4 + 2) * 16 + colq]);
        fma4(acc, xv.w, wlds[(4 * k4 + 3) * 16 + colq]);
    }
    ((float4*)(h1 + (size_t)row * H_DIM))[colq] = acc;
}

// ---------- gather layer 1: one wave per node, lane = feature ----------
// Stage neighbor (idx, dinv) in lane registers, broadcast via shfl; issue 8
// independent h1-row loads before their fmas => deep MLP, latency off the chain.
__global__ __launch_bounds__(256) void k_gather1(const int* __restrict__ csr_src,
                                                 const int* __restrict__ base,
                                                 const int* __restrict__ cnt,
                                                 const float* __restrict__ dinv,
                                                 const float* __restrict__ h1,
                                                 const float* __restrict__ b1,
                                                 float* __restrict__ agg1) {
    int wid  = (blockIdx.x * blockDim.x + threadIdx.x) >> 6;   // node id
    int lane = threadIdx.x & 63;
    if (wid >= N_NODES) return;
    int   b  = base[wid];
    int   c  = cnt[wid];
    float di = dinv[wid];
    float acc = di * h1[(size_t)wid * H_DIM + lane];

    for (int k0 = 0; k0 < c; k0 += 64) {
        int nj = min(64, c - k0);
        int   sidx = 0;
        float dn   = 0.f;
        int k = k0 + lane;
        if (k < c) { sidx = csr_src[b + k]; dn = dinv[sidx]; }   // coalesced + parallel

        int j = 0;
        for (; j + 8 <= nj; j += 8) {
            // issue 8 independent row loads
            float v0 = h1[(size_t)__shfl(sidx, j + 0) * H_DIM + lane];
            float v1 = h1[(size_t)__shfl(sidx, j + 1) * H_DIM + lane];
            float v2 = h1[(size_t)__shfl(sidx, j + 2) * H_DIM + lane];
            float v3 = h1[(size_t)__shfl(sidx, j + 3) * H_DIM + lane];
            float v4 = h1[(size_t)__shfl(sidx, j + 4) * H_DIM + lane];
            float v5 = h1[(size_t)__shfl(sidx, j + 5) * H_DIM + lane];
            float v6 = h1[(size_t)__shfl(sidx, j + 6) * H_DIM + lane];
            float v7 = h1[(size_t)__shfl(sidx, j + 7) * H_DIM + lane];
            acc = fmaf(__shfl(dn, j + 0), v0, acc);
            acc = fmaf(__shfl(dn, j + 1), v1, acc);
            acc = fmaf(__shfl(dn, j + 2), v2, acc);
            acc = fmaf(__shfl(dn, j + 3), v3, acc);
            acc = fmaf(__shfl(dn, j + 4), v4, acc);
            acc = fmaf(__shfl(dn, j + 5), v5, acc);
            acc = fmaf(__shfl(dn, j + 6), v6, acc);
            acc = fmaf(__shfl(dn, j + 7), v7, acc);
        }
        for (; j < nj; ++j) {
            acc = fmaf(__shfl(dn, j),
                       h1[(size_t)__shfl(sidx, j) * H_DIM + lane], acc);
        }
    }
    agg1[(size_t)wid * H_DIM + lane] = fmaf(di, acc, b1[lane]);
}

// ---------- GEMM2: h2[N,16] = relu(agg1)[N,64] @ W2[64,16] ----------
__global__ __launch_bounds__(256) void k_gemm2(const float* __restrict__ hpre,
                                               const float* __restrict__ W2,
                                               float* __restrict__ h2) {
    __shared__ float4 wlds[H_DIM * 4];                // 4 KB
    int tid = threadIdx.x;
    if (tid < H_DIM * 4) wlds[tid] = ((const float4*)W2)[tid];
    __syncthreads();

    int row = blockIdx.x * 64 + (tid >> 2);
    if (row >= N_NODES) return;
    int colq = tid & 3;
    const float4* h4 = (const float4*)(hpre + (size_t)row * H_DIM);
    float4 acc = {0.f, 0.f, 0.f, 0.f};
    #pragma unroll
    for (int k4 = 0; k4 < H_DIM / 4; ++k4) {
        float4 hv = h4[k4];
        hv.x = fmaxf(hv.x, 0.f); hv.y = fmaxf(hv.y, 0.f);
        hv.z = fmaxf(hv.z, 0.f); hv.w = fmaxf(hv.w, 0.f);
        fma4(acc, hv.x, wlds[(4 * k4 + 0) * 4 + colq]);
        fma4(acc, hv.y, wlds[(4 * k4 + 1) * 4 + colq]);
        fma4(acc, hv.z, wlds[(4 * k4 + 2) * 4 + colq]);
        fma4(acc, hv.w, wlds[(4 * k4 + 3) * 4 + colq]);
    }
    ((float4*)(h2 + (size_t)row * C_DIM))[colq] = acc;
}

// ---------- gather layer 2: 16-lane group per node, staged indices ----------
__global__ __launch_bounds__(256) void k_gather2(const int* __restrict__ csr_src,
                                                 const int* __restrict__ base,
                                                 const int* __restrict__ cnt,
                                                 const float* __restrict__ dinv,
                                                 const float* __restrict__ h2,
                                                 const float* __restrict__ b2,
                                                 float* __restrict__ out) {
    int node = (blockIdx.x * blockDim.x + threadIdx.x) >> 4;
    int lane = threadIdx.x & 15;
    int gb   = threadIdx.x & 48;              // group base lane within wave
    if (node >= N_NODES) return;
    int   b  = base[node];
    int   c  = cnt[node];
    float di = dinv[node];
    float acc = di * h2[(size_t)node * C_DIM + lane];

    for (int k0 = 0; k0 < c; k0 += 16) {
        int nj = min(16, c - k0);
        int   sidx = 0;
        float dn   = 0.f;
        int k = k0 + lane;
        if (k < c) { sidx = csr_src[b + k]; dn = dinv[sidx]; }

        int j = 0;
        for (; j + 4 <= nj; j += 4) {
            float v0 = h2[(size_t)__shfl(sidx, gb + j + 0) * C_DIM + lane];
            float v1 = h2[(size_t)__shfl(sidx, gb + j + 1) * C_DIM + lane];
            float v2 = h2[(size_t)__shfl(sidx, gb + j + 2) * C_DIM + lane];
            float v3 = h2[(size_t)__shfl(sidx, gb + j + 3) * C_DIM + lane];
            acc = fmaf(__shfl(dn, gb + j + 0), v0, acc);
            acc = fmaf(__shfl(dn, gb + j + 1), v1, acc);
            acc = fmaf(__shfl(dn, gb + j + 2), v2, acc);
            acc = fmaf(__shfl(dn, gb + j + 3), v3, acc);
        }
        for (; j < nj; ++j) {
            acc = fmaf(__shfl(dn, gb + j),
                       h2[(size_t)__shfl(sidx, gb + j) * C_DIM + lane], acc);
        }
    }
    out[(size_t)node * C_DIM + lane] = fmaf(di, acc, b2[lane]);
}

extern "C" void kernel_launch(void* const* d_in, const int* in_sizes, int n_in,
                              void* d_out, int out_size, void* d_ws, size_t ws_size,
                              hipStream_t stream) {
    const float* x     = (const float*)d_in[0];
    const int*   edges = (const int*)d_in[1];              // int32 (harness converts)
    const float* W1    = (const float*)d_in[2];
    const float* b1    = (const float*)d_in[3];
    const float* W2    = (const float*)d_in[4];
    const float* b2    = (const float*)d_in[5];
    float*       out   = (float*)d_out;

    const int E = in_sizes[1] / 2;                         // 3,200,000

    // workspace (~65.4 MB):
    // region A (25.6 MB): pairs (CSR build), then h1/h2 (pairs dead after k_bnode)
    float* h1      = (float*)d_ws;                         // N*64 f32
    int2*  pairs   = (int2*)d_ws;                          // E int2 (same bytes)
    float* agg1    = h1 + (size_t)N_NODES * H_DIM;         // N*64 f32
    int*   csr_src = (int*)(agg1 + (size_t)N_NODES * H_DIM); // E
    int*   nbase   = csr_src + E;                          // N
    int*   ncnt    = nbase + N_NODES;                      // N
    float* dinv    = (float*)(ncnt + N_NODES);             // N
    int*   bkt_tot = (int*)(dinv + N_NODES);               // NBKT*16
    int*   bkt_base= bkt_tot + NBKT * BKT_PAD;             // NBKT
    int*   bkt_tail= bkt_base + NBKT;                      // NBKT*16
    float* h2      = h1;

    const int nchunk = (E + CHUNK - 1) / CHUNK;            // 782

    // CSR build (bucketed counting sort by dst)
    k_zero_b <<<(NBKT * BKT_PAD + 255) / 256, 256, 0, stream>>>(bkt_tot);
    k_bhist  <<<nchunk, 256, 0, stream>>>((const int2*)edges, bkt_tot, E);
    k_bscan  <<<1, 512, 0, stream>>>(bkt_tot, bkt_base, bkt_tail);
    k_bfill  <<<nchunk, 256, 0, stream>>>((const int2*)edges, bkt_tail, pairs, E);
    k_bnode  <<<NBKT, 256, 0, stream>>>(pairs, bkt_base, csr_src, nbase, ncnt, dinv, E);

    // layer 1
    k_gemm1   <<<N_NODES / 16, 256, 0, stream>>>(x, W1, h1);
    k_gather1 <<<(N_NODES * 64 + 255) / 256, 256, 0, stream>>>(csr_src, nbase, ncnt,
                                                               dinv, h1, b1, agg1);

    // layer 2 (relu fused into gemm2 load)
    k_gemm2   <<<(N_NODES + 63) / 64, 256, 0, stream>>>(agg1, W2, h2);
    k_gather2 <<<(N_NODES * 16 + 255) / 256, 256, 0, stream>>>(csr_src, nbase, ncnt,
                                                               dinv, h2, b2, out);
}